// Round 1
// baseline (1141.814 us; speedup 1.0000x reference)
//
#include <hip/hip_runtime.h>
#include <math.h>

#define BB 8
#define LL 1024
#define DD 512
#define VV 64
#define KK 8

constexpr float INV_TEMP = 10.0f;   // 1/TEMP
constexpr float EPSF     = 1e-10f;

// ---------------- workspace float layout ----------------
// 0: cls_sum   1: cls_cnt
// 2: ptr_sum   3: ptr_cnt
// 4..11:  empty bce sum per b
// 12..19: empty att count per b
// 20: row_sum  21: row_cnt  22: col_sum  23: col_cnt
// 24..24+8192: den[b*L + l]
#define WS_DEN 24
#define WS_FLOATS (24 + BB*LL)

// ---------------- bool-dtype detection ----------------
// attention_mask[:, :L] is all-True, so the first elements tell us the width.
__device__ __forceinline__ int mask_mode(const void* att_raw) {
    const unsigned* w = (const unsigned*)att_raw;
    unsigned w0 = w[0];
    if (w0 == 0x01010101u) return 0;           // bool/uint8
    if (w0 == 0x3f800000u) return 2;           // float32
    if (w0 == 1u) return (w[1] == 0u) ? 3 : 1; // int64 : int32
    return 0;
}
__device__ __forceinline__ bool get_mask(const void* p, int idx, int mode) {
    if (mode == 0) return ((const unsigned char*)p)[idx] != 0;
    if (mode == 1) return ((const int*)p)[idx] != 0;
    if (mode == 3) return ((const unsigned*)p)[2*idx] != 0u;
    return ((const float*)p)[idx] != 0.0f;
}

// ---------------- wave reductions (wave64) ----------------
__device__ __forceinline__ float wave_red_sum(float v) {
    #pragma unroll
    for (int off = 32; off; off >>= 1) v += __shfl_xor(v, off);
    return v;
}
__device__ __forceinline__ float wave_red_max(float v) {
    #pragma unroll
    for (int off = 32; off; off >>= 1) v = fmaxf(v, __shfl_xor(v, off));
    return v;
}

// ================= cls_loss: row softmax over V=64 =================
__global__ void k_cls(const float* __restrict__ logits, const int* __restrict__ tok,
                      float* __restrict__ ws) {
    int row  = blockIdx.x * (blockDim.x >> 6) + (threadIdx.x >> 6);
    int lane = threadIdx.x & 63;
    if (row >= BB * LL) return;
    float x  = logits[(size_t)row * VV + lane];
    float mx = wave_red_max(x);
    float se = wave_red_sum(__expf(x - mx));
    float sx = wave_red_sum(x);
    float logZ = mx + logf(se);
    int t = tok[row];
    float xt = __shfl(x, t);
    float nll    = logZ - xt;
    float smooth = logZ - sx * (1.0f / VV);
    float per = 0.9f * nll + 0.1f * smooth;
    bool valid = (t > 3);
    if (lane == 0) {
        atomicAdd(&ws[0], valid ? per : 0.0f);
        atomicAdd(&ws[1], valid ? 1.0f : 0.0f);
    }
}

// ================= den: fused GEMM + masked exp row-sum =================
// den[b,l] = sum_t dtm[b,t] * exp( dot(box[b,l,:], tag[b,t,:]) * 10 )
#define TLT 64
#define TTT 64
#define DCH 32
#define TSPLIT 4
__global__ __launch_bounds__(256) void k_den(const float* __restrict__ box,
                                             const float* __restrict__ tag,
                                             const void* __restrict__ dtm_raw,
                                             const void* __restrict__ att_raw,
                                             float* __restrict__ ws) {
    __shared__ float a_s[DCH][TLT + 4];   // [d][l], padded
    __shared__ float b_s[DCH][TTT + 4];   // [d][t], padded

    int bid    = blockIdx.x;
    int tsplit = bid & (TSPLIT - 1);
    int ltile  = (bid >> 2) & (LL / TLT - 1);
    int b      = bid >> 6;               // 16 ltiles * 4 splits = 64 per b
    int l0      = ltile * TLT;
    int t_begin = tsplit * (LL / TSPLIT);

    int mode = mask_mode(att_raw);
    int tid  = threadIdx.x;
    int lane = tid & 63, wave = tid >> 6;
    int tx = lane & 15;                  // t sub-tile
    int ty = (wave << 2) | (lane >> 4);  // l sub-tile, 0..15

    const float* boxb = box + (size_t)b * LL * DD;
    const float* tagb = tag + (size_t)b * LL * DD;

    int lrow = tid >> 2;   // 0..63 : row loaded by this thread
    int dq   = tid & 3;    // 0..3  : which 8-float d-slice

    float den_acc[4] = {0.f, 0.f, 0.f, 0.f};

    for (int tt = 0; tt < LL / TSPLIT; tt += TTT) {
        int t0 = t_begin + tt;
        float acc[4][4];
        #pragma unroll
        for (int i = 0; i < 4; i++)
            #pragma unroll
            for (int j = 0; j < 4; j++) acc[i][j] = 0.0f;

        for (int d0 = 0; d0 < DD; d0 += DCH) {
            __syncthreads();   // protect previous chunk's reads
            const float4* pa = (const float4*)(boxb + (size_t)(l0 + lrow) * DD + d0 + dq * 8);
            float4 va0 = pa[0], va1 = pa[1];
            const float4* pb = (const float4*)(tagb + (size_t)(t0 + lrow) * DD + d0 + dq * 8);
            float4 vb0 = pb[0], vb1 = pb[1];
            int db = dq * 8;
            a_s[db + 0][lrow] = va0.x; a_s[db + 1][lrow] = va0.y;
            a_s[db + 2][lrow] = va0.z; a_s[db + 3][lrow] = va0.w;
            a_s[db + 4][lrow] = va1.x; a_s[db + 5][lrow] = va1.y;
            a_s[db + 6][lrow] = va1.z; a_s[db + 7][lrow] = va1.w;
            b_s[db + 0][lrow] = vb0.x; b_s[db + 1][lrow] = vb0.y;
            b_s[db + 2][lrow] = vb0.z; b_s[db + 3][lrow] = vb0.w;
            b_s[db + 4][lrow] = vb1.x; b_s[db + 5][lrow] = vb1.y;
            b_s[db + 6][lrow] = vb1.z; b_s[db + 7][lrow] = vb1.w;
            __syncthreads();
            #pragma unroll
            for (int d = 0; d < DCH; d++) {
                float4 av = *(const float4*)&a_s[d][ty * 4];
                float4 bv = *(const float4*)&b_s[d][tx * 4];
                acc[0][0] += av.x * bv.x; acc[0][1] += av.x * bv.y;
                acc[0][2] += av.x * bv.z; acc[0][3] += av.x * bv.w;
                acc[1][0] += av.y * bv.x; acc[1][1] += av.y * bv.y;
                acc[1][2] += av.y * bv.z; acc[1][3] += av.y * bv.w;
                acc[2][0] += av.z * bv.x; acc[2][1] += av.z * bv.y;
                acc[2][2] += av.z * bv.z; acc[2][3] += av.z * bv.w;
                acc[3][0] += av.w * bv.x; acc[3][1] += av.w * bv.y;
                acc[3][2] += av.w * bv.z; acc[3][3] += av.w * bv.w;
            }
        }
        // exp + mask + reduce over t for this tile
        #pragma unroll
        for (int i = 0; i < 4; i++) {
            float s = 0.0f;
            #pragma unroll
            for (int j = 0; j < 4; j++) {
                int t = t0 + tx * 4 + j;
                bool m = get_mask(dtm_raw, b * (2 * LL) + LL + t, mode);
                s += m ? __expf(acc[i][j] * INV_TEMP) : 0.0f;
            }
            #pragma unroll
            for (int off = 1; off < 16; off <<= 1) s += __shfl_xor(s, off);
            den_acc[i] += s;
        }
    }
    if (tx == 0) {
        #pragma unroll
        for (int i = 0; i < 4; i++)
            atomicAdd(&ws[WS_DEN + b * LL + l0 + ty * 4 + i], den_acc[i]);
    }
}

// ================= ptr terms: gather l_tgt and accumulate =================
__global__ void k_ptr(const float* __restrict__ box, const float* __restrict__ tag,
                      const int* __restrict__ bidx,
                      const void* __restrict__ dtm_raw, const void* __restrict__ att_raw,
                      float* __restrict__ ws) {
    int row  = blockIdx.x * 4 + (threadIdx.x >> 6);   // b*L + l
    int lane = threadIdx.x & 63;
    int b = row >> 10;
    int mode = mask_mode(att_raw);
    float den = ws[WS_DEN + row];
    float logden = logf(den + EPSF);
    const float4* bp = (const float4*)(box + (size_t)row * DD + lane * 8);
    float4 x0 = bp[0], x1 = bp[1];
    float lsum = 0.0f, lcnt = 0.0f;
    bool running = true;
    for (int k = 0; k < KK; k++) {
        int idx = bidx[row * KK + k];
        running = running && (idx != -1);
        int rel  = idx - LL;
        int relc = min(max(rel, 0), LL - 1);
        bool dg = get_mask(dtm_raw, b * (2 * LL) + LL + relc, mode);
        bool m = running && dg;
        if (m) {
            const float4* tp = (const float4*)(tag + ((size_t)b * LL + relc) * DD + lane * 8);
            float4 y0 = tp[0], y1 = tp[1];
            float d = x0.x * y0.x + x0.y * y0.y + x0.z * y0.z + x0.w * y0.w
                    + x1.x * y1.x + x1.y * y1.y + x1.z * y1.z + x1.w * y1.w;
            d = wave_red_sum(d);
            lsum += logden - d * INV_TEMP;
            lcnt += 1.0f;
        }
    }
    if (lane == 0) {
        atomicAdd(&ws[2], lsum);
        atomicAdd(&ws[3], lcnt);
    }
}

// ================= empty pointer BCE =================
__global__ void k_empty(const float* __restrict__ emptyp, const float* __restrict__ tag,
                        const void* __restrict__ dtm_raw, const void* __restrict__ att_raw,
                        float* __restrict__ ws) {
    int row  = blockIdx.x * 4 + (threadIdx.x >> 6);   // b*L + t
    int lane = threadIdx.x & 63;
    int b = row >> 10, t = row & 1023;
    int mode = mask_mode(att_raw);
    bool att = get_mask(att_raw, b * (2 * LL) + LL + t, mode);
    if (!att) return;
    const float4* ep = (const float4*)(emptyp + (size_t)b * DD + lane * 8);
    const float4* tp = (const float4*)(tag + (size_t)row * DD + lane * 8);
    float4 e0 = ep[0], e1 = ep[1], y0 = tp[0], y1 = tp[1];
    float d = e0.x * y0.x + e0.y * y0.y + e0.z * y0.z + e0.w * y0.w
            + e1.x * y1.x + e1.y * y1.y + e1.z * y1.z + e1.w * y1.w;
    d = wave_red_sum(d);
    bool dtm = get_mask(dtm_raw, b * (2 * LL) + LL + t, mode);
    float tgt = dtm ? 0.0f : 1.0f;   // att & ~dtm (att is true here)
    float sp  = fmaxf(d, 0.0f) + log1pf(expf(-fabsf(d)));
    float bce = sp - d * tgt;
    if (lane == 0) {
        atomicAdd(&ws[4 + b],  bce);
        atomicAdd(&ws[12 + b], 1.0f);
    }
}

// ================= span contrastive (row & col in one kernel) =================
__global__ void k_contr(const float* __restrict__ row_sim, const float* __restrict__ col_sim,
                        const float* __restrict__ row_coef, const float* __restrict__ col_coef,
                        float* __restrict__ ws) {
    int gw   = blockIdx.x * 4 + (threadIdx.x >> 6);
    int lane = threadIdx.x & 63;
    int mat  = gw >> 13;           // 0: row, 1: col
    int row  = gw & 8191;          // b*L + j
    int j    = row & 1023;
    const float* sim  = (mat ? col_sim  : row_sim)  + (size_t)row * LL;
    const float* coef = (mat ? col_coef : row_coef) + (size_t)row * LL;

    float x[16];
    #pragma unroll
    for (int e = 0; e < 4; e++) {
        float4 v = ((const float4*)sim)[e * 64 + lane];
        x[e*4+0] = v.x; x[e*4+1] = v.y; x[e*4+2] = v.z; x[e*4+3] = v.w;
    }
    float lmx = -1e30f;
    #pragma unroll
    for (int i = 0; i < 16; i++) { x[i] *= INV_TEMP; lmx = fmaxf(lmx, x[i]); }
    float mx = wave_red_max(lmx);

    float se = 0.0f, diag = 0.0f;
    #pragma unroll
    for (int e = 0; e < 4; e++) {
        #pragma unroll
        for (int q = 0; q < 4; q++) {
            int t = e * 256 + lane * 4 + q;
            float v = __expf(x[e*4+q] - mx);
            se += v;
            if (t == j) diag = v;
        }
    }
    se   = wave_red_sum(se);
    diag = wave_red_sum(diag);
    float logden = logf(se - diag + EPSF);

    float sw = 0.0f, sws = 0.0f;
    #pragma unroll
    for (int e = 0; e < 4; e++) {
        float4 c = ((const float4*)coef)[e * 64 + lane];
        float cv[4] = {c.x, c.y, c.z, c.w};
        #pragma unroll
        for (int q = 0; q < 4; q++) {
            float w = cv[q] > 0.0f ? cv[q] : 0.0f;
            sw  += w;
            sws += w * (x[e*4+q] - mx);
        }
    }
    sw  = wave_red_sum(sw);
    sws = wave_red_sum(sws);
    bool hp = sw > 0.0f;
    float loss = (logden * sw - sws) / (sw + EPSF);
    if (lane == 0) {
        atomicAdd(&ws[20 + mat * 2], hp ? loss : 0.0f);
        atomicAdd(&ws[21 + mat * 2], hp ? 1.0f : 0.0f);
    }
}

// ================= final combine =================
__global__ void k_final(const float* __restrict__ ws, float* __restrict__ out) {
    if (threadIdx.x == 0 && blockIdx.x == 0) {
        float cls = ws[0] / fmaxf(ws[1], 1.0f);
        float ptr = (ws[3] > 0.0f) ? ws[2] / fmaxf(ws[3], 1.0f) : 0.0f;
        float emp = 0.0f;
        for (int b = 0; b < BB; b++) emp += ws[4 + b] / fmaxf(ws[12 + b], 1.0f);
        emp *= (1.0f / BB);
        float rc = (ws[21] > 0.0f) ? ws[20] / fmaxf(ws[21], 1.0f) : 0.0f;
        float cc = (ws[23] > 0.0f) ? ws[22] / fmaxf(ws[23], 1.0f) : 0.0f;
        float tot = cls + ptr + emp + 0.5f * (rc + cc);
        out[0] = tot; out[1] = cls; out[2] = ptr;
        out[3] = emp; out[4] = rc;  out[5] = cc;
    }
}

extern "C" void kernel_launch(void* const* d_in, const int* in_sizes, int n_in,
                              void* d_out, int out_size, void* d_ws, size_t ws_size,
                              hipStream_t stream) {
    (void)in_sizes; (void)n_in; (void)out_size; (void)ws_size;
    const int*   token_ids = (const int*)  d_in[0];
    const int*   box_idx   = (const int*)  d_in[1];
    const void*  dtm       =               d_in[2];
    const void*  att       =               d_in[3];
    const float* tag_log   = (const float*)d_in[4];
    const float* box_proj  = (const float*)d_in[5];
    const float* tag_proj  = (const float*)d_in[6];
    const float* empty_p   = (const float*)d_in[7];
    const float* row_sim   = (const float*)d_in[8];
    const float* col_sim   = (const float*)d_in[9];
    const float* row_coef  = (const float*)d_in[10];
    const float* col_coef  = (const float*)d_in[11];
    float* ws  = (float*)d_ws;
    float* out = (float*)d_out;

    hipMemsetAsync(d_ws, 0, WS_FLOATS * sizeof(float), stream);

    k_cls  <<<BB * LL / 4, 256, 0, stream>>>(tag_log, token_ids, ws);
    k_den  <<<BB * (LL / TLT) * TSPLIT, 256, 0, stream>>>(box_proj, tag_proj, dtm, att, ws);
    k_ptr  <<<BB * LL / 4, 256, 0, stream>>>(box_proj, tag_proj, box_idx, dtm, att, ws);
    k_empty<<<BB * LL / 4, 256, 0, stream>>>(empty_p, tag_proj, dtm, att, ws);
    k_contr<<<2 * BB * LL / 4, 256, 0, stream>>>(row_sim, col_sim, row_coef, col_coef, ws);
    k_final<<<1, 64, 0, stream>>>(ws, out);
}

// Round 2
// 209.377 us; speedup vs baseline: 5.4534x; 5.4534x over previous
//
#include <hip/hip_runtime.h>
#include <math.h>

#define BB 8
#define LL 1024
#define DD 512
#define VV 64
#define KK 8

constexpr float INV_TEMP = 10.0f;   // 1/TEMP
constexpr float EPSF     = 1e-10f;

// ---------------- workspace float layout ----------------
// [0..2048):    256 buckets x 8 quantities (bucket*8+q), one line per 2 buckets
//               q: 0 cls_sum, 1 cls_cnt, 2 ptr_sum, 3 ptr_cnt,
//                  4 row_sum, 5 row_cnt, 6 col_sum, 7 col_cnt
// [2048..2560): empty BCE buckets: (b*32 + (t&31))*2 + {sum,cnt}
// [2560..10752): den[b*L + l]
#define WS_EMPTY 2048
#define WS_DEN   2560
#define WS_FLOATS (WS_DEN + BB*LL)

// ---------------- bool-dtype detection ----------------
// attention_mask[:, :L] is all-True, so the first elements tell us the width.
__device__ __forceinline__ int mask_mode(const void* att_raw) {
    const unsigned* w = (const unsigned*)att_raw;
    unsigned w0 = w[0];
    if (w0 == 0x01010101u) return 0;           // bool/uint8
    if (w0 == 0x3f800000u) return 2;           // float32
    if (w0 == 1u) return (w[1] == 0u) ? 3 : 1; // int64 : int32
    return 0;
}
__device__ __forceinline__ bool get_mask(const void* p, int idx, int mode) {
    if (mode == 0) return ((const unsigned char*)p)[idx] != 0;
    if (mode == 1) return ((const int*)p)[idx] != 0;
    if (mode == 3) return ((const unsigned*)p)[2*idx] != 0u;
    return ((const float*)p)[idx] != 0.0f;
}

// ---------------- wave reductions (wave64) ----------------
__device__ __forceinline__ float wave_red_sum(float v) {
    #pragma unroll
    for (int off = 32; off; off >>= 1) v += __shfl_xor(v, off);
    return v;
}
__device__ __forceinline__ float wave_red_max(float v) {
    #pragma unroll
    for (int off = 32; off; off >>= 1) v = fmaxf(v, __shfl_xor(v, off));
    return v;
}

// ================= cls_loss: row softmax over V=64 =================
__global__ void k_cls(const float* __restrict__ logits, const int* __restrict__ tok,
                      float* __restrict__ ws) {
    int row  = blockIdx.x * (blockDim.x >> 6) + (threadIdx.x >> 6);
    int lane = threadIdx.x & 63;
    if (row >= BB * LL) return;
    float x  = logits[(size_t)row * VV + lane];
    float mx = wave_red_max(x);
    float se = wave_red_sum(__expf(x - mx));
    float sx = wave_red_sum(x);
    float logZ = mx + logf(se);
    int t = tok[row];
    float xt = __shfl(x, t);
    float nll    = logZ - xt;
    float smooth = logZ - sx * (1.0f / VV);
    float per = 0.9f * nll + 0.1f * smooth;
    bool valid = (t > 3);
    if (lane == 0) {
        int bkt = (row & 255) * 8;
        atomicAdd(&ws[bkt + 0], valid ? per : 0.0f);
        atomicAdd(&ws[bkt + 1], valid ? 1.0f : 0.0f);
    }
}

// ================= den: fused GEMM + masked exp row-sum =================
// den[b,l] = sum_t dtm[b,t] * exp( dot(box[b,l,:], tag[b,t,:]) * 10 )
#define TLT 64
#define TTT 64
#define DCH 32
#define TSPLIT 4
__global__ __launch_bounds__(256) void k_den(const float* __restrict__ box,
                                             const float* __restrict__ tag,
                                             const void* __restrict__ dtm_raw,
                                             const void* __restrict__ att_raw,
                                             float* __restrict__ ws) {
    __shared__ float a_s[DCH][TLT + 4];   // [d][l], padded
    __shared__ float b_s[DCH][TTT + 4];   // [d][t], padded

    int bid    = blockIdx.x;
    int tsplit = bid & (TSPLIT - 1);
    int ltile  = (bid >> 2) & (LL / TLT - 1);
    int b      = bid >> 6;               // 16 ltiles * 4 splits = 64 per b
    int l0      = ltile * TLT;
    int t_begin = tsplit * (LL / TSPLIT);

    int mode = mask_mode(att_raw);
    int tid  = threadIdx.x;
    int lane = tid & 63, wave = tid >> 6;
    int tx = lane & 15;                  // t sub-tile
    int ty = (wave << 2) | (lane >> 4);  // l sub-tile, 0..15

    const float* boxb = box + (size_t)b * LL * DD;
    const float* tagb = tag + (size_t)b * LL * DD;

    int lrow = tid >> 2;   // 0..63 : row loaded by this thread
    int dq   = tid & 3;    // 0..3  : which 8-float d-slice

    float den_acc[4] = {0.f, 0.f, 0.f, 0.f};

    for (int tt = 0; tt < LL / TSPLIT; tt += TTT) {
        int t0 = t_begin + tt;
        float acc[4][4];
        #pragma unroll
        for (int i = 0; i < 4; i++)
            #pragma unroll
            for (int j = 0; j < 4; j++) acc[i][j] = 0.0f;

        for (int d0 = 0; d0 < DD; d0 += DCH) {
            __syncthreads();   // protect previous chunk's reads
            const float4* pa = (const float4*)(boxb + (size_t)(l0 + lrow) * DD + d0 + dq * 8);
            float4 va0 = pa[0], va1 = pa[1];
            const float4* pb = (const float4*)(tagb + (size_t)(t0 + lrow) * DD + d0 + dq * 8);
            float4 vb0 = pb[0], vb1 = pb[1];
            int db = dq * 8;
            a_s[db + 0][lrow] = va0.x; a_s[db + 1][lrow] = va0.y;
            a_s[db + 2][lrow] = va0.z; a_s[db + 3][lrow] = va0.w;
            a_s[db + 4][lrow] = va1.x; a_s[db + 5][lrow] = va1.y;
            a_s[db + 6][lrow] = va1.z; a_s[db + 7][lrow] = va1.w;
            b_s[db + 0][lrow] = vb0.x; b_s[db + 1][lrow] = vb0.y;
            b_s[db + 2][lrow] = vb0.z; b_s[db + 3][lrow] = vb0.w;
            b_s[db + 4][lrow] = vb1.x; b_s[db + 5][lrow] = vb1.y;
            b_s[db + 6][lrow] = vb1.z; b_s[db + 7][lrow] = vb1.w;
            __syncthreads();
            #pragma unroll
            for (int d = 0; d < DCH; d++) {
                float4 av = *(const float4*)&a_s[d][ty * 4];
                float4 bv = *(const float4*)&b_s[d][tx * 4];
                acc[0][0] += av.x * bv.x; acc[0][1] += av.x * bv.y;
                acc[0][2] += av.x * bv.z; acc[0][3] += av.x * bv.w;
                acc[1][0] += av.y * bv.x; acc[1][1] += av.y * bv.y;
                acc[1][2] += av.y * bv.z; acc[1][3] += av.y * bv.w;
                acc[2][0] += av.z * bv.x; acc[2][1] += av.z * bv.y;
                acc[2][2] += av.z * bv.z; acc[2][3] += av.z * bv.w;
                acc[3][0] += av.w * bv.x; acc[3][1] += av.w * bv.y;
                acc[3][2] += av.w * bv.z; acc[3][3] += av.w * bv.w;
            }
        }
        // exp + mask + reduce over t for this tile
        #pragma unroll
        for (int i = 0; i < 4; i++) {
            float s = 0.0f;
            #pragma unroll
            for (int j = 0; j < 4; j++) {
                int t = t0 + tx * 4 + j;
                bool m = get_mask(dtm_raw, b * (2 * LL) + LL + t, mode);
                s += m ? __expf(acc[i][j] * INV_TEMP) : 0.0f;
            }
            #pragma unroll
            for (int off = 1; off < 16; off <<= 1) s += __shfl_xor(s, off);
            den_acc[i] += s;
        }
    }
    if (tx == 0) {
        #pragma unroll
        for (int i = 0; i < 4; i++)
            atomicAdd(&ws[WS_DEN + b * LL + l0 + ty * 4 + i], den_acc[i]);
    }
}

// ================= ptr terms: gather l_tgt and accumulate =================
__global__ void k_ptr(const float* __restrict__ box, const float* __restrict__ tag,
                      const int* __restrict__ bidx,
                      const void* __restrict__ dtm_raw, const void* __restrict__ att_raw,
                      float* __restrict__ ws) {
    int row  = blockIdx.x * 4 + (threadIdx.x >> 6);   // b*L + l
    int lane = threadIdx.x & 63;
    int b = row >> 10;
    int mode = mask_mode(att_raw);
    float den = ws[WS_DEN + row];
    float logden = logf(den + EPSF);
    const float4* bp = (const float4*)(box + (size_t)row * DD + lane * 8);
    float4 x0 = bp[0], x1 = bp[1];
    float lsum = 0.0f, lcnt = 0.0f;
    bool running = true;
    for (int k = 0; k < KK; k++) {
        int idx = bidx[row * KK + k];
        running = running && (idx != -1);
        int rel  = idx - LL;
        int relc = min(max(rel, 0), LL - 1);
        bool dg = get_mask(dtm_raw, b * (2 * LL) + LL + relc, mode);
        bool m = running && dg;
        if (m) {
            const float4* tp = (const float4*)(tag + ((size_t)b * LL + relc) * DD + lane * 8);
            float4 y0 = tp[0], y1 = tp[1];
            float d = x0.x * y0.x + x0.y * y0.y + x0.z * y0.z + x0.w * y0.w
                    + x1.x * y1.x + x1.y * y1.y + x1.z * y1.z + x1.w * y1.w;
            d = wave_red_sum(d);
            lsum += logden - d * INV_TEMP;
            lcnt += 1.0f;
        }
    }
    if (lane == 0) {
        int bkt = (row & 255) * 8;
        atomicAdd(&ws[bkt + 2], lsum);
        atomicAdd(&ws[bkt + 3], lcnt);
    }
}

// ================= empty pointer BCE =================
__global__ void k_empty(const float* __restrict__ emptyp, const float* __restrict__ tag,
                        const void* __restrict__ dtm_raw, const void* __restrict__ att_raw,
                        float* __restrict__ ws) {
    int row  = blockIdx.x * 4 + (threadIdx.x >> 6);   // b*L + t
    int lane = threadIdx.x & 63;
    int b = row >> 10, t = row & 1023;
    int mode = mask_mode(att_raw);
    bool att = get_mask(att_raw, b * (2 * LL) + LL + t, mode);
    if (!att) return;
    const float4* ep = (const float4*)(emptyp + (size_t)b * DD + lane * 8);
    const float4* tp = (const float4*)(tag + (size_t)row * DD + lane * 8);
    float4 e0 = ep[0], e1 = ep[1], y0 = tp[0], y1 = tp[1];
    float d = e0.x * y0.x + e0.y * y0.y + e0.z * y0.z + e0.w * y0.w
            + e1.x * y1.x + e1.y * y1.y + e1.z * y1.z + e1.w * y1.w;
    d = wave_red_sum(d);
    bool dtm = get_mask(dtm_raw, b * (2 * LL) + LL + t, mode);
    float tgt = dtm ? 0.0f : 1.0f;   // att & ~dtm (att is true here)
    float sp  = fmaxf(d, 0.0f) + log1pf(expf(-fabsf(d)));
    float bce = sp - d * tgt;
    if (lane == 0) {
        int e = WS_EMPTY + (b * 32 + (t & 31)) * 2;
        atomicAdd(&ws[e + 0], bce);
        atomicAdd(&ws[e + 1], 1.0f);
    }
}

// ================= span contrastive (row & col in one kernel) =================
__global__ void k_contr(const float* __restrict__ row_sim, const float* __restrict__ col_sim,
                        const float* __restrict__ row_coef, const float* __restrict__ col_coef,
                        float* __restrict__ ws) {
    int gw   = blockIdx.x * 4 + (threadIdx.x >> 6);
    int lane = threadIdx.x & 63;
    int mat  = gw >> 13;           // 0: row, 1: col
    int row  = gw & 8191;          // b*L + j
    int j    = row & 1023;
    const float* sim  = (mat ? col_sim  : row_sim)  + (size_t)row * LL;
    const float* coef = (mat ? col_coef : row_coef) + (size_t)row * LL;

    float x[16];
    #pragma unroll
    for (int e = 0; e < 4; e++) {
        float4 v = ((const float4*)sim)[e * 64 + lane];
        x[e*4+0] = v.x; x[e*4+1] = v.y; x[e*4+2] = v.z; x[e*4+3] = v.w;
    }
    float lmx = -1e30f;
    #pragma unroll
    for (int i = 0; i < 16; i++) { x[i] *= INV_TEMP; lmx = fmaxf(lmx, x[i]); }
    float mx = wave_red_max(lmx);

    float se = 0.0f, diag = 0.0f;
    #pragma unroll
    for (int e = 0; e < 4; e++) {
        #pragma unroll
        for (int q = 0; q < 4; q++) {
            int t = e * 256 + lane * 4 + q;
            float v = __expf(x[e*4+q] - mx);
            se += v;
            if (t == j) diag = v;
        }
    }
    se   = wave_red_sum(se);
    diag = wave_red_sum(diag);
    float logden = logf(se - diag + EPSF);

    float sw = 0.0f, sws = 0.0f;
    #pragma unroll
    for (int e = 0; e < 4; e++) {
        float4 c = ((const float4*)coef)[e * 64 + lane];
        float cv[4] = {c.x, c.y, c.z, c.w};
        #pragma unroll
        for (int q = 0; q < 4; q++) {
            float w = cv[q] > 0.0f ? cv[q] : 0.0f;
            sw  += w;
            sws += w * (x[e*4+q] - mx);
        }
    }
    sw  = wave_red_sum(sw);
    sws = wave_red_sum(sws);
    bool hp = sw > 0.0f;
    float loss = (logden * sw - sws) / (sw + EPSF);
    if (lane == 0) {
        int bkt = (row & 255) * 8 + 4 + mat * 2;
        atomicAdd(&ws[bkt + 0], hp ? loss : 0.0f);
        atomicAdd(&ws[bkt + 1], hp ? 1.0f : 0.0f);
    }
}

// ================= final combine (reduce buckets) =================
__global__ void k_final(const float* __restrict__ ws, float* __restrict__ out) {
    __shared__ float lds[4][8];
    __shared__ float eb[8][2];
    int tid  = threadIdx.x;         // 256 threads
    int lane = tid & 63, wave = tid >> 6;

    float q[8];
    #pragma unroll
    for (int i = 0; i < 8; i++) q[i] = ws[tid * 8 + i];
    #pragma unroll
    for (int i = 0; i < 8; i++) {
        #pragma unroll
        for (int off = 32; off; off >>= 1) q[i] += __shfl_xor(q[i], off);
    }
    if (lane == 0) {
        #pragma unroll
        for (int i = 0; i < 8; i++) lds[wave][i] = q[i];
    }
    // empty buckets: 256 pairs, 32 per b
    float es = ws[WS_EMPTY + tid * 2 + 0];
    float ec = ws[WS_EMPTY + tid * 2 + 1];
    #pragma unroll
    for (int off = 16; off; off >>= 1) { es += __shfl_xor(es, off); ec += __shfl_xor(ec, off); }
    if ((tid & 31) == 0) { eb[tid >> 5][0] = es; eb[tid >> 5][1] = ec; }
    __syncthreads();
    if (tid == 0) {
        float s[8];
        #pragma unroll
        for (int i = 0; i < 8; i++)
            s[i] = lds[0][i] + lds[1][i] + lds[2][i] + lds[3][i];
        float cls = s[0] / fmaxf(s[1], 1.0f);
        float ptr = (s[3] > 0.0f) ? s[2] / fmaxf(s[3], 1.0f) : 0.0f;
        float emp = 0.0f;
        for (int b = 0; b < BB; b++) emp += eb[b][0] / fmaxf(eb[b][1], 1.0f);
        emp *= (1.0f / BB);
        float rc = (s[5] > 0.0f) ? s[4] / fmaxf(s[5], 1.0f) : 0.0f;
        float cc = (s[7] > 0.0f) ? s[6] / fmaxf(s[7], 1.0f) : 0.0f;
        float tot = cls + ptr + emp + 0.5f * (rc + cc);
        out[0] = tot; out[1] = cls; out[2] = ptr;
        out[3] = emp; out[4] = rc;  out[5] = cc;
    }
}

extern "C" void kernel_launch(void* const* d_in, const int* in_sizes, int n_in,
                              void* d_out, int out_size, void* d_ws, size_t ws_size,
                              hipStream_t stream) {
    (void)in_sizes; (void)n_in; (void)out_size; (void)ws_size;
    const int*   token_ids = (const int*)  d_in[0];
    const int*   box_idx   = (const int*)  d_in[1];
    const void*  dtm       =               d_in[2];
    const void*  att       =               d_in[3];
    const float* tag_log   = (const float*)d_in[4];
    const float* box_proj  = (const float*)d_in[5];
    const float* tag_proj  = (const float*)d_in[6];
    const float* empty_p   = (const float*)d_in[7];
    const float* row_sim   = (const float*)d_in[8];
    const float* col_sim   = (const float*)d_in[9];
    const float* row_coef  = (const float*)d_in[10];
    const float* col_coef  = (const float*)d_in[11];
    float* ws  = (float*)d_ws;
    float* out = (float*)d_out;

    hipMemsetAsync(d_ws, 0, WS_FLOATS * sizeof(float), stream);

    k_cls  <<<BB * LL / 4, 256, 0, stream>>>(tag_log, token_ids, ws);
    k_den  <<<BB * (LL / TLT) * TSPLIT, 256, 0, stream>>>(box_proj, tag_proj, dtm, att, ws);
    k_ptr  <<<BB * LL / 4, 256, 0, stream>>>(box_proj, tag_proj, box_idx, dtm, att, ws);
    k_empty<<<BB * LL / 4, 256, 0, stream>>>(empty_p, tag_proj, dtm, att, ws);
    k_contr<<<2 * BB * LL / 4, 256, 0, stream>>>(row_sim, col_sim, row_coef, col_coef, ws);
    k_final<<<1, 64, 0, stream>>>(ws, out);
}

// Round 4
// 94.881 us; speedup vs baseline: 12.0341x; 2.2067x over previous
//
#include <hip/hip_runtime.h>
#include <hip/hip_bf16.h>
#include <math.h>

#define BB 8
#define LL 1024
#define DD 512
#define VV 64
#define KK 8

constexpr float INV_TEMP = 10.0f;   // 1/TEMP
constexpr float EPSF     = 1e-10f;

// ---------------- workspace float layout ----------------
// [0..2048):    256 buckets x 8 quantities (bucket*8+q)
//               q: 0 cls_sum, 1 cls_cnt, 2 ptr_sum, 3 ptr_cnt,
//                  4 row_sum, 5 row_cnt, 6 col_sum, 7 col_cnt
// [2048..2560): empty BCE buckets: (b*32 + (t&31))*2 + {sum,cnt}
// [2560..10752): den[b*L + l]
#define WS_EMPTY 2048
#define WS_DEN   2560
#define WS_FLOATS (WS_DEN + BB*LL)

typedef __attribute__((ext_vector_type(8))) short  short8;
typedef __attribute__((ext_vector_type(4))) float  f32x4;

// ---------------- bool-dtype detection ----------------
// MUST be fed attention_mask: its first L entries are all-True by construction.
// (data_tag_mask's first L entries are all-False — detection on it is garbage.)
__device__ __forceinline__ int mask_mode(const void* att_raw) {
    const unsigned* w = (const unsigned*)att_raw;
    unsigned w0 = w[0];
    if (w0 == 0x01010101u) return 0;           // bool/uint8
    if (w0 == 0x3f800000u) return 2;           // float32
    if (w0 == 1u) return (w[1] == 0u) ? 3 : 1; // int64 : int32
    return 0;
}
__device__ __forceinline__ bool get_mask(const void* p, int idx, int mode) {
    if (mode == 0) return ((const unsigned char*)p)[idx] != 0;
    if (mode == 1) return ((const int*)p)[idx] != 0;
    if (mode == 3) return ((const unsigned*)p)[2*idx] != 0u;
    return ((const float*)p)[idx] != 0.0f;
}

// ---------------- wave reductions (wave64) ----------------
__device__ __forceinline__ float wave_red_sum(float v) {
    #pragma unroll
    for (int off = 32; off; off >>= 1) v += __shfl_xor(v, off);
    return v;
}
__device__ __forceinline__ float wave_red_max(float v) {
    #pragma unroll
    for (int off = 32; off; off >>= 1) v = fmaxf(v, __shfl_xor(v, off));
    return v;
}

__device__ __forceinline__ short bfb(float f) {
    __hip_bfloat16 h = __float2bfloat16(f);   // RNE; compiler fuses pairs to v_cvt_pk_bf16_f32
    union { __hip_bfloat16 h; short u; } c; c.h = h; return c.u;
}

// ================= cls_loss: row softmax over V=64 =================
__global__ void k_cls(const float* __restrict__ logits, const int* __restrict__ tok,
                      float* __restrict__ ws) {
    int row  = blockIdx.x * (blockDim.x >> 6) + (threadIdx.x >> 6);
    int lane = threadIdx.x & 63;
    if (row >= BB * LL) return;
    float x  = logits[(size_t)row * VV + lane];
    float mx = wave_red_max(x);
    float se = wave_red_sum(__expf(x - mx));
    float sx = wave_red_sum(x);
    float logZ = mx + logf(se);
    int t = tok[row];
    float xt = __shfl(x, t);
    float nll    = logZ - xt;
    float smooth = logZ - sx * (1.0f / VV);
    float per = 0.9f * nll + 0.1f * smooth;
    bool valid = (t > 3);
    if (lane == 0) {
        int bkt = (row & 255) * 8;
        atomicAdd(&ws[bkt + 0], valid ? per : 0.0f);
        atomicAdd(&ws[bkt + 1], valid ? 1.0f : 0.0f);
    }
}

// ================= den: bf16 MFMA GEMM + masked exp row-sum =================
// den[b,l] = sum_t dtm[b,t] * exp( dot(box[b,l,:], tag[b,t,:]) * 10 )
// 128x128 tile per block, 4 waves in 2x2 of 64x64, BK=32 bf16,
// reg-staged f32->bf16 conversion, LDS rows padded to 80B (2-way banks = free).
#define BM 128
#define BKD 32
#define ST 40            // LDS row stride in shorts (80 bytes)
__global__ __launch_bounds__(256) void k_den(const float* __restrict__ box,
                                             const float* __restrict__ tag,
                                             const void* __restrict__ dtm_raw,
                                             const void* __restrict__ att_raw,
                                             float* __restrict__ ws) {
    __shared__ short As[BM * ST];
    __shared__ short Bs[BM * ST];

    int bid   = blockIdx.x;
    int b     = bid & 7;              // batch -> XCD affinity (L2 locality)
    int tile  = bid >> 3;             // 0..63
    int l0    = (tile >> 3) * BM;
    int t0    = (tile & 7) * BM;

    int tid  = threadIdx.x;
    int lane = tid & 63;
    int wave = tid >> 6;
    int wr   = wave >> 1, wc = wave & 1;

    // staging assignment: thread -> (row, 16-float half of BK=32)
    int srow = tid >> 1;
    int shalf = tid & 1;
    const float* gA = box + ((size_t)b * LL + l0 + srow) * DD + shalf * 16;
    const float* gB = tag + ((size_t)b * LL + t0 + srow) * DD + shalf * 16;
    short* wA = &As[srow * ST + shalf * 16];
    short* wB = &Bs[srow * ST + shalf * 16];

    f32x4 acc[4][4];
    #pragma unroll
    for (int m = 0; m < 4; m++)
        #pragma unroll
        for (int n = 0; n < 4; n++) acc[m][n] = (f32x4){0.f, 0.f, 0.f, 0.f};

    int k0 = (lane >> 4) * 8;                 // k-offset of this lane's fragment
    const short* rA = &As[(wr * 64 + (lane & 15)) * ST + k0];
    const short* rB = &Bs[(wc * 64 + (lane & 15)) * ST + k0];

    for (int d0 = 0; d0 < DD; d0 += BKD) {
        __syncthreads();   // protect previous iteration's fragment reads
        float4 fa0 = *(const float4*)(gA + d0);
        float4 fa1 = *(const float4*)(gA + d0 + 4);
        float4 fa2 = *(const float4*)(gA + d0 + 8);
        float4 fa3 = *(const float4*)(gA + d0 + 12);
        float4 fb0 = *(const float4*)(gB + d0);
        float4 fb1 = *(const float4*)(gB + d0 + 4);
        float4 fb2 = *(const float4*)(gB + d0 + 8);
        float4 fb3 = *(const float4*)(gB + d0 + 12);
        short8 va0 = {bfb(fa0.x), bfb(fa0.y), bfb(fa0.z), bfb(fa0.w),
                      bfb(fa1.x), bfb(fa1.y), bfb(fa1.z), bfb(fa1.w)};
        short8 va1 = {bfb(fa2.x), bfb(fa2.y), bfb(fa2.z), bfb(fa2.w),
                      bfb(fa3.x), bfb(fa3.y), bfb(fa3.z), bfb(fa3.w)};
        short8 vb0 = {bfb(fb0.x), bfb(fb0.y), bfb(fb0.z), bfb(fb0.w),
                      bfb(fb1.x), bfb(fb1.y), bfb(fb1.z), bfb(fb1.w)};
        short8 vb1 = {bfb(fb2.x), bfb(fb2.y), bfb(fb2.z), bfb(fb2.w),
                      bfb(fb3.x), bfb(fb3.y), bfb(fb3.z), bfb(fb3.w)};
        *(short8*)wA       = va0;
        *(short8*)(wA + 8) = va1;
        *(short8*)wB       = vb0;
        *(short8*)(wB + 8) = vb1;
        __syncthreads();

        short8 af[4], bf[4];
        #pragma unroll
        for (int m = 0; m < 4; m++) af[m] = *(const short8*)(rA + m * 16 * ST);
        #pragma unroll
        for (int n = 0; n < 4; n++) bf[n] = *(const short8*)(rB + n * 16 * ST);
        #pragma unroll
        for (int m = 0; m < 4; m++)
            #pragma unroll
            for (int n = 0; n < 4; n++)
                acc[m][n] = __builtin_amdgcn_mfma_f32_16x16x32_bf16(af[m], bf[n], acc[m][n], 0, 0, 0);
    }

    // epilogue: exp + dtm mask + row-sum over this block's 128 t-columns
    int mode = mask_mode(att_raw);    // detect width on attention_mask (all-True head)
    bool mk[4];
    #pragma unroll
    for (int n = 0; n < 4; n++) {
        int t = t0 + wc * 64 + n * 16 + (lane & 15);
        mk[n] = get_mask(dtm_raw, b * (2 * LL) + LL + t, mode);
    }
    #pragma unroll
    for (int m = 0; m < 4; m++) {
        #pragma unroll
        for (int reg = 0; reg < 4; reg++) {
            float s = 0.0f;
            #pragma unroll
            for (int n = 0; n < 4; n++)
                s += mk[n] ? __expf(acc[m][n][reg] * INV_TEMP) : 0.0f;
            // reduce across the 16 lanes holding different t (lane&15 varies)
            #pragma unroll
            for (int off = 1; off < 16; off <<= 1) s += __shfl_xor(s, off);
            if ((lane & 15) == 0) {
                int l = l0 + wr * 64 + m * 16 + (lane >> 4) * 4 + reg;
                atomicAdd(&ws[WS_DEN + b * LL + l], s);
            }
        }
    }
}

// ================= ptr terms: gather l_tgt and accumulate =================
__global__ void k_ptr(const float* __restrict__ box, const float* __restrict__ tag,
                      const int* __restrict__ bidx,
                      const void* __restrict__ dtm_raw, const void* __restrict__ att_raw,
                      float* __restrict__ ws) {
    int row  = blockIdx.x * 4 + (threadIdx.x >> 6);   // b*L + l
    int lane = threadIdx.x & 63;
    int b = row >> 10;
    int mode = mask_mode(att_raw);
    float den = ws[WS_DEN + row];
    float logden = logf(den + EPSF);
    const float4* bp = (const float4*)(box + (size_t)row * DD + lane * 8);
    float4 x0 = bp[0], x1 = bp[1];
    float lsum = 0.0f, lcnt = 0.0f;
    bool running = true;
    for (int k = 0; k < KK; k++) {
        int idx = bidx[row * KK + k];
        running = running && (idx != -1);
        int rel  = idx - LL;
        int relc = min(max(rel, 0), LL - 1);
        bool dg = get_mask(dtm_raw, b * (2 * LL) + LL + relc, mode);
        bool m = running && dg;
        if (m) {
            const float4* tp = (const float4*)(tag + ((size_t)b * LL + relc) * DD + lane * 8);
            float4 y0 = tp[0], y1 = tp[1];
            float d = x0.x * y0.x + x0.y * y0.y + x0.z * y0.z + x0.w * y0.w
                    + x1.x * y1.x + x1.y * y1.y + x1.z * y1.z + x1.w * y1.w;
            d = wave_red_sum(d);
            lsum += logden - d * INV_TEMP;
            lcnt += 1.0f;
        }
    }
    if (lane == 0) {
        int bkt = (row & 255) * 8;
        atomicAdd(&ws[bkt + 2], lsum);
        atomicAdd(&ws[bkt + 3], lcnt);
    }
}

// ================= empty pointer BCE =================
__global__ void k_empty(const float* __restrict__ emptyp, const float* __restrict__ tag,
                        const void* __restrict__ dtm_raw, const void* __restrict__ att_raw,
                        float* __restrict__ ws) {
    int row  = blockIdx.x * 4 + (threadIdx.x >> 6);   // b*L + t
    int lane = threadIdx.x & 63;
    int b = row >> 10, t = row & 1023;
    int mode = mask_mode(att_raw);
    bool att = get_mask(att_raw, b * (2 * LL) + LL + t, mode);
    if (!att) return;
    const float4* ep = (const float4*)(emptyp + (size_t)b * DD + lane * 8);
    const float4* tp = (const float4*)(tag + (size_t)row * DD + lane * 8);
    float4 e0 = ep[0], e1 = ep[1], y0 = tp[0], y1 = tp[1];
    float d = e0.x * y0.x + e0.y * y0.y + e0.z * y0.z + e0.w * y0.w
            + e1.x * y1.x + e1.y * y1.y + e1.z * y1.z + e1.w * y1.w;
    d = wave_red_sum(d);
    bool dtm = get_mask(dtm_raw, b * (2 * LL) + LL + t, mode);
    float tgt = dtm ? 0.0f : 1.0f;   // att & ~dtm (att is true here)
    float sp  = fmaxf(d, 0.0f) + log1pf(expf(-fabsf(d)));
    float bce = sp - d * tgt;
    if (lane == 0) {
        int e = WS_EMPTY + (b * 32 + (t & 31)) * 2;
        atomicAdd(&ws[e + 0], bce);
        atomicAdd(&ws[e + 1], 1.0f);
    }
}

// ================= span contrastive (row & col in one kernel) =================
__global__ void k_contr(const float* __restrict__ row_sim, const float* __restrict__ col_sim,
                        const float* __restrict__ row_coef, const float* __restrict__ col_coef,
                        float* __restrict__ ws) {
    int gw   = blockIdx.x * 4 + (threadIdx.x >> 6);
    int lane = threadIdx.x & 63;
    int mat  = gw >> 13;           // 0: row, 1: col
    int row  = gw & 8191;          // b*L + j
    int j    = row & 1023;
    const float* sim  = (mat ? col_sim  : row_sim)  + (size_t)row * LL;
    const float* coef = (mat ? col_coef : row_coef) + (size_t)row * LL;

    float x[16];
    #pragma unroll
    for (int e = 0; e < 4; e++) {
        float4 v = ((const float4*)sim)[e * 64 + lane];
        x[e*4+0] = v.x; x[e*4+1] = v.y; x[e*4+2] = v.z; x[e*4+3] = v.w;
    }
    float lmx = -1e30f;
    #pragma unroll
    for (int i = 0; i < 16; i++) { x[i] *= INV_TEMP; lmx = fmaxf(lmx, x[i]); }
    float mx = wave_red_max(lmx);

    float se = 0.0f, diag = 0.0f;
    #pragma unroll
    for (int e = 0; e < 4; e++) {
        #pragma unroll
        for (int q = 0; q < 4; q++) {
            int t = e * 256 + lane * 4 + q;
            float v = __expf(x[e*4+q] - mx);
            se += v;
            if (t == j) diag = v;
        }
    }
    se   = wave_red_sum(se);
    diag = wave_red_sum(diag);
    float logden = logf(se - diag + EPSF);

    float sw = 0.0f, sws = 0.0f;
    #pragma unroll
    for (int e = 0; e < 4; e++) {
        float4 c = ((const float4*)coef)[e * 64 + lane];
        float cv[4] = {c.x, c.y, c.z, c.w};
        #pragma unroll
        for (int q = 0; q < 4; q++) {
            float w = cv[q] > 0.0f ? cv[q] : 0.0f;
            sw  += w;
            sws += w * (x[e*4+q] - mx);
        }
    }
    sw  = wave_red_sum(sw);
    sws = wave_red_sum(sws);
    bool hp = sw > 0.0f;
    float loss = (logden * sw - sws) / (sw + EPSF);
    if (lane == 0) {
        int bkt = (row & 255) * 8 + 4 + mat * 2;
        atomicAdd(&ws[bkt + 0], hp ? loss : 0.0f);
        atomicAdd(&ws[bkt + 1], hp ? 1.0f : 0.0f);
    }
}

// ================= final combine (reduce buckets) =================
__global__ void k_final(const float* __restrict__ ws, float* __restrict__ out) {
    __shared__ float lds[4][8];
    __shared__ float eb[8][2];
    int tid  = threadIdx.x;         // 256 threads
    int lane = tid & 63, wave = tid >> 6;

    float q[8];
    #pragma unroll
    for (int i = 0; i < 8; i++) q[i] = ws[tid * 8 + i];
    #pragma unroll
    for (int i = 0; i < 8; i++) {
        #pragma unroll
        for (int off = 32; off; off >>= 1) q[i] += __shfl_xor(q[i], off);
    }
    if (lane == 0) {
        #pragma unroll
        for (int i = 0; i < 8; i++) lds[wave][i] = q[i];
    }
    // empty buckets: 256 pairs, 32 per b
    float es = ws[WS_EMPTY + tid * 2 + 0];
    float ec = ws[WS_EMPTY + tid * 2 + 1];
    #pragma unroll
    for (int off = 16; off; off >>= 1) { es += __shfl_xor(es, off); ec += __shfl_xor(ec, off); }
    if ((tid & 31) == 0) { eb[tid >> 5][0] = es; eb[tid >> 5][1] = ec; }
    __syncthreads();
    if (tid == 0) {
        float s[8];
        #pragma unroll
        for (int i = 0; i < 8; i++)
            s[i] = lds[0][i] + lds[1][i] + lds[2][i] + lds[3][i];
        float cls = s[0] / fmaxf(s[1], 1.0f);
        float ptr = (s[3] > 0.0f) ? s[2] / fmaxf(s[3], 1.0f) : 0.0f;
        float emp = 0.0f;
        for (int b = 0; b < BB; b++) emp += eb[b][0] / fmaxf(eb[b][1], 1.0f);
        emp *= (1.0f / BB);
        float rc = (s[5] > 0.0f) ? s[4] / fmaxf(s[5], 1.0f) : 0.0f;
        float cc = (s[7] > 0.0f) ? s[6] / fmaxf(s[7], 1.0f) : 0.0f;
        float tot = cls + ptr + emp + 0.5f * (rc + cc);
        out[0] = tot; out[1] = cls; out[2] = ptr;
        out[3] = emp; out[4] = rc;  out[5] = cc;
    }
}

extern "C" void kernel_launch(void* const* d_in, const int* in_sizes, int n_in,
                              void* d_out, int out_size, void* d_ws, size_t ws_size,
                              hipStream_t stream) {
    (void)in_sizes; (void)n_in; (void)out_size; (void)ws_size;
    const int*   token_ids = (const int*)  d_in[0];
    const int*   box_idx   = (const int*)  d_in[1];
    const void*  dtm       =               d_in[2];
    const void*  att       =               d_in[3];
    const float* tag_log   = (const float*)d_in[4];
    const float* box_proj  = (const float*)d_in[5];
    const float* tag_proj  = (const float*)d_in[6];
    const float* empty_p   = (const float*)d_in[7];
    const float* row_sim   = (const float*)d_in[8];
    const float* col_sim   = (const float*)d_in[9];
    const float* row_coef  = (const float*)d_in[10];
    const float* col_coef  = (const float*)d_in[11];
    float* ws  = (float*)d_ws;
    float* out = (float*)d_out;

    hipMemsetAsync(d_ws, 0, WS_FLOATS * sizeof(float), stream);

    k_cls  <<<BB * LL / 4, 256, 0, stream>>>(tag_log, token_ids, ws);
    k_den  <<<BB * 64, 256, 0, stream>>>(box_proj, tag_proj, dtm, att, ws);
    k_ptr  <<<BB * LL / 4, 256, 0, stream>>>(box_proj, tag_proj, box_idx, dtm, att, ws);
    k_empty<<<BB * LL / 4, 256, 0, stream>>>(empty_p, tag_proj, dtm, att, ws);
    k_contr<<<2 * BB * LL / 4, 256, 0, stream>>>(row_sim, col_sim, row_coef, col_coef, ws);
    k_final<<<1, 64, 0, stream>>>(ws, out);
}